// Round 1
// baseline (388.414 us; speedup 1.0000x reference)
//
#include <hip/hip_runtime.h>
#include <hip/hip_bf16.h>

#define B_ 8
#define D_ 128
#define L_ 1024
#define KSZ 7
#define NH_ 8
#define DK_ 16

constexpr int BD = D_ * L_;                 // 131072 elements per batch
constexpr float LN_EPS = 1e-5f;
constexpr float INV_N = 1.0f / (float)BD;

// ---------- helpers ----------

__device__ __forceinline__ float2 ln_stats(const float2* __restrict__ part, int b, int npart) {
    float s = 0.f, q = 0.f;
    for (int i = 0; i < npart; ++i) { float2 p = part[b * 32 + i]; s += p.x; q += p.y; }
    float m = s * INV_N;
    float v = q * INV_N - m * m;
    return make_float2(m, rsqrtf(v + LN_EPS));
}

__device__ __forceinline__ void block_reduce_write(float s, float q, float2* slot, int tid) {
    __shared__ float reds[256];
    __shared__ float redq[256];
    reds[tid] = s; redq[tid] = q;
    __syncthreads();
    for (int off = 128; off > 0; off >>= 1) {
        if (tid < off) { reds[tid] += reds[tid + off]; redq[tid] += redq[tid + off]; }
        __syncthreads();
    }
    if (tid == 0) *slot = make_float2(reds[0], redq[0]);
}

// ---------- pos-enc add + stats ----------
// grid (16, 8), block 256; each block covers 8192 contiguous elements of one batch
__global__ __launch_bounds__(256) void k_addpos(
    const float* __restrict__ x, const float* __restrict__ pos,
    float* __restrict__ out, float2* __restrict__ part)
{
    int b = blockIdx.y, blk = blockIdx.x, tid = threadIdx.x;
    int base = b * BD + blk * 8192;
    int pbase = blk * 8192;
    const float4* x4 = (const float4*)(x + base);
    const float4* p4 = (const float4*)(pos + pbase);
    float4* o4 = (float4*)(out + base);
    float s = 0.f, q = 0.f;
    #pragma unroll
    for (int j = 0; j < 8; ++j) {
        int idx = j * 256 + tid;
        float4 xv = x4[idx], pv = p4[idx];
        float4 r = {xv.x + pv.x, xv.y + pv.y, xv.z + pv.z, xv.w + pv.w};
        o4[idx] = r;
        s += r.x + r.y + r.z + r.w;
        q += r.x * r.x + r.y * r.y + r.z * r.z + r.w * r.w;
    }
    block_reduce_write(s, q, part + b * 32 + blk, tid);
}

// ---------- LayerNorm apply (+ stats of output) ----------
__global__ __launch_bounds__(256) void k_ln_apply(
    const float* __restrict__ in, const float* __restrict__ lnw, const float* __restrict__ lnb,
    float* __restrict__ out, const float2* __restrict__ part_in, int npart,
    float2* __restrict__ part_out)
{
    int b = blockIdx.y, blk = blockIdx.x, tid = threadIdx.x;
    float2 st = ln_stats(part_in, b, npart);
    float mean = st.x, rstd = st.y;
    int base = b * BD + blk * 8192;
    int pbase = blk * 8192;
    const float4* i4  = (const float4*)(in + base);
    const float4* w4  = (const float4*)(lnw + pbase);
    const float4* bb4 = (const float4*)(lnb + pbase);
    float4* o4 = (float4*)(out + base);
    float s = 0.f, q = 0.f;
    #pragma unroll
    for (int j = 0; j < 8; ++j) {
        int idx = j * 256 + tid;
        float4 xv = i4[idx], w = w4[idx], bb = bb4[idx];
        float4 r;
        r.x = (xv.x - mean) * rstd * w.x + bb.x;
        r.y = (xv.y - mean) * rstd * w.y + bb.y;
        r.z = (xv.z - mean) * rstd * w.z + bb.z;
        r.w = (xv.w - mean) * rstd * w.w + bb.w;
        o4[idx] = r;
        s += r.x + r.y + r.z + r.w;
        q += r.x * r.x + r.y * r.y + r.z * r.z + r.w * r.w;
    }
    block_reduce_write(s, q, part_out + b * 32 + blk, tid);
}

// ---------- fused LayerNorm + depthwise conv (K=7, zero pad) ----------
// grid 1024 (= b*128+d rows), block 256
__global__ __launch_bounds__(256) void k_ln_dw(
    const float* __restrict__ in, const float* __restrict__ lnw, const float* __restrict__ lnb,
    const float* __restrict__ dwk, float* __restrict__ out,
    const float2* __restrict__ part, int npart)
{
    int blk = blockIdx.x;
    int b = blk >> 7, d = blk & 127;
    int tid = threadIdx.x;
    float2 st = ln_stats(part, b, npart);
    float mean = st.x, rstd = st.y;
    __shared__ float row[L_ + 8];
    const float* inr = in + b * BD + d * L_;
    const float* wr  = lnw + d * L_;
    const float* br  = lnb + d * L_;
    #pragma unroll
    for (int j = 0; j < 4; ++j) {
        int l = j * 256 + tid;
        row[3 + l] = (inr[l] - mean) * rstd * wr[l] + br[l];
    }
    if (tid < 3) { row[tid] = 0.f; row[L_ + 3 + tid] = 0.f; }
    __syncthreads();
    float k0 = dwk[d*KSZ+0], k1 = dwk[d*KSZ+1], k2 = dwk[d*KSZ+2], k3 = dwk[d*KSZ+3],
          k4 = dwk[d*KSZ+4], k5 = dwk[d*KSZ+5], k6 = dwk[d*KSZ+6];
    float* outr = out + b * BD + d * L_;
    #pragma unroll
    for (int j = 0; j < 4; ++j) {
        int l = j * 256 + tid;
        outr[l] = k0*row[l]   + k1*row[l+1] + k2*row[l+2] + k3*row[l+3]
                + k4*row[l+4] + k5*row[l+5] + k6*row[l+6];
    }
}

// ---------- per-batch 128x128 @ 128x1024 matmul ----------
// WMODE 0: W[o,c] shared over b   (pointwise conv)
// WMODE 1: W[b,o,c] per batch     (Wo, final W)
// WMODE 2: W[h,b,dk,c], o=h*16+dk (Wq/Wk/Wv gather)
// grid (16 ltiles, 2 rowblocks, 8 b), block 256; 64x64 tile, 4x4 per thread
template<int WMODE, bool RELU, bool ADDRES, bool STATS>
__global__ __launch_bounds__(256) void k_matmul(
    const float* __restrict__ Wm, const float* __restrict__ X,
    const float* res, float* out, float2* part)
{
    int lt = blockIdx.x, rb = blockIdx.y, b = blockIdx.z;
    int tid = threadIdx.x;
    int l0 = lt * 64, r0 = rb * 64;
    __shared__ float Ws[D_][64];   // [c][o_local] (transposed)
    __shared__ float Xs[D_][64];   // [c][l_local]
    #pragma unroll
    for (int j = 0; j < 32; ++j) {
        int e = j * 256 + tid;
        int o = e & 63, c = e >> 6;
        int og = r0 + o;
        int woff;
        if constexpr (WMODE == 0)      woff = og * D_ + c;
        else if constexpr (WMODE == 1) woff = b * D_ * D_ + og * D_ + c;
        else                           woff = (og >> 4) * (B_ * DK_ * D_) + b * (DK_ * D_) + (og & 15) * D_ + c;
        Ws[c][o] = Wm[woff];
        Xs[c][o] = X[b * BD + c * L_ + l0 + o];
    }
    __syncthreads();
    int ty = tid >> 4, tx = tid & 15;   // rows ty*4.., cols tx*4..
    float acc[4][4];
    #pragma unroll
    for (int r = 0; r < 4; ++r)
        #pragma unroll
        for (int j = 0; j < 4; ++j) acc[r][j] = 0.f;
    #pragma unroll 4
    for (int c = 0; c < D_; ++c) {
        float4 wv4 = *(const float4*)(&Ws[c][ty * 4]);
        float4 xv4 = *(const float4*)(&Xs[c][tx * 4]);
        float wv[4] = {wv4.x, wv4.y, wv4.z, wv4.w};
        float xv[4] = {xv4.x, xv4.y, xv4.z, xv4.w};
        #pragma unroll
        for (int r = 0; r < 4; ++r)
            #pragma unroll
            for (int j = 0; j < 4; ++j) acc[r][j] += wv[r] * xv[j];
    }
    float s = 0.f, q = 0.f;
    #pragma unroll
    for (int r = 0; r < 4; ++r) {
        int og = r0 + ty * 4 + r;
        float v[4];
        #pragma unroll
        for (int j = 0; j < 4; ++j) { v[j] = acc[r][j]; if constexpr (RELU) v[j] = fmaxf(v[j], 0.f); }
        if constexpr (ADDRES) {
            float4 rv = *(const float4*)(&res[b * BD + og * L_ + l0 + tx * 4]);
            v[0] += rv.x; v[1] += rv.y; v[2] += rv.z; v[3] += rv.w;
        }
        float4 ov = {v[0], v[1], v[2], v[3]};
        *(float4*)(&out[b * BD + og * L_ + l0 + tx * 4]) = ov;
        if constexpr (STATS) {
            s += v[0] + v[1] + v[2] + v[3];
            q += v[0]*v[0] + v[1]*v[1] + v[2]*v[2] + v[3]*v[3];
        }
    }
    if constexpr (STATS) block_reduce_write(s, q, part + b * 32 + rb * 16 + lt, tid);
}

// ---------- attention: softmax over l (query axis) per output column m ----------
// out[b, h*16+v, m] = sum_l V[v,l] * softmax_l(Q[:,l]·K[:,m] / 4)
// grid (4 mtiles, NH, B), block 256; each thread owns one m; online softmax over l.
__global__ __launch_bounds__(256) void k_attn(
    const float* __restrict__ Qb, const float* __restrict__ Kb,
    const float* __restrict__ Vb, float* __restrict__ outb)
{
    int mt = blockIdx.x, h = blockIdx.y, b = blockIdx.z;
    int tid = threadIdx.x;
    int m = mt * 256 + tid;
    const float* Qp = Qb + b * BD + (h * DK_) * L_;
    const float* Kp = Kb + b * BD + (h * DK_) * L_;
    const float* Vp = Vb + b * BD + (h * DK_) * L_;
    __shared__ float Qs[DK_][128];
    __shared__ float Vs[DK_][128];
    float kreg[DK_];
    #pragma unroll
    for (int d = 0; d < DK_; ++d) kreg[d] = Kp[d * L_ + m] * 0.25f;  // fold 1/sqrt(DK)
    float mx = -1e30f, sm = 0.f;
    float acc[DK_];
    #pragma unroll
    for (int v = 0; v < DK_; ++v) acc[v] = 0.f;
    for (int lt = 0; lt < 8; ++lt) {
        __syncthreads();
        #pragma unroll
        for (int j = 0; j < 8; ++j) {
            int e = j * 256 + tid;
            int d = e >> 7, l = e & 127;
            Qs[d][l] = Qp[d * L_ + lt * 128 + l];
            Vs[d][l] = Vp[d * L_ + lt * 128 + l];
        }
        __syncthreads();
        for (int lc = 0; lc < 128; lc += 16) {
            float sv[16];
            #pragma unroll
            for (int j = 0; j < 16; ++j) sv[j] = 0.f;
            #pragma unroll
            for (int d = 0; d < DK_; ++d) {
                float kd = kreg[d];
                const float* qrow = &Qs[d][lc];
                #pragma unroll
                for (int j = 0; j < 16; ++j) sv[j] += kd * qrow[j];
            }
            float cm = mx;
            #pragma unroll
            for (int j = 0; j < 16; ++j) cm = fmaxf(cm, sv[j]);
            float fac = __expf(mx - cm);
            float wsum = 0.f;
            #pragma unroll
            for (int j = 0; j < 16; ++j) { sv[j] = __expf(sv[j] - cm); wsum += sv[j]; }
            sm = sm * fac + wsum;
            mx = cm;
            #pragma unroll
            for (int v = 0; v < DK_; ++v) {
                float a = acc[v] * fac;
                const float* vrow = &Vs[v][lc];
                #pragma unroll
                for (int j = 0; j < 16; ++j) a += sv[j] * vrow[j];
                acc[v] = a;
            }
        }
    }
    float inv = 1.f / sm;
    #pragma unroll
    for (int v = 0; v < DK_; ++v)
        outb[b * BD + (h * DK_ + v) * L_ + m] = acc[v] * inv;
}

// ---------- launch ----------

extern "C" void kernel_launch(void* const* d_in, const int* in_sizes, int n_in,
                              void* d_out, int out_size, void* d_ws, size_t ws_size,
                              hipStream_t stream)
{
    const float* x   = (const float*)d_in[0];
    const float* pos = (const float*)d_in[1];
    const float* lnw = (const float*)d_in[2];
    const float* lnb = (const float*)d_in[3];
    const float* dw  = (const float*)d_in[4];
    const float* pw  = (const float*)d_in[5];
    const float* Wq  = (const float*)d_in[6];
    const float* Wk  = (const float*)d_in[7];
    const float* Wv  = (const float*)d_in[8];
    const float* Wo  = (const float*)d_in[9];
    const float* Wf  = (const float*)d_in[10];
    float* out = (float*)d_out;

    float* ws = (float*)d_ws;
    float2* P1 = (float2*)ws;               // 256 float2
    float2* P2 = (float2*)(ws + 512);       // 256 float2
    float* buf_res = ws + 1024;             // residual stream c_i
    float* buf_ln  = buf_res + (size_t)B_ * BD;
    float* buf_dw  = buf_ln  + (size_t)B_ * BD;  // depthwise out; later attn heads
    float* buf_q   = buf_dw  + (size_t)B_ * BD;
    float* buf_k   = buf_q   + (size_t)B_ * BD;
    float* buf_v   = buf_k   + (size_t)B_ * BD;

    dim3 eg(16, 8);        // elementwise grids
    dim3 mb(16, 2, 8);     // matmul grid

    // out = x + pos; res = out  (+stats for first LN)
    k_addpos<<<eg, 256, 0, stream>>>(x, pos, buf_res, P1);

    for (int i = 0; i < 4; ++i) {
        const float* src = (i == 0) ? buf_res : buf_ln;
        // dwout = depthwise(LN(src))
        k_ln_dw<<<1024, 256, 0, stream>>>(src, lnw, lnb, dw + i * D_ * KSZ, buf_dw, P1, 16);
        // c_i = relu(pw_i @ dwout) + res  (+stats of c_i)
        k_matmul<0, true, true, true><<<mb, 256, 0, stream>>>(pw + i * D_ * D_, buf_dw, buf_res, buf_res, P2);
        // b_i = LN(c_i)  (+stats of b_i for next iteration's LN)
        k_ln_apply<<<eg, 256, 0, stream>>>(buf_res, lnw, lnb, buf_ln, P2, 32, P1);
    }

    // Q/K/V = Wq/Wk/Wv (gathered per b) @ b_3
    k_matmul<2, false, false, false><<<mb, 256, 0, stream>>>(Wq, buf_ln, nullptr, buf_q, nullptr);
    k_matmul<2, false, false, false><<<mb, 256, 0, stream>>>(Wk, buf_ln, nullptr, buf_k, nullptr);
    k_matmul<2, false, false, false><<<mb, 256, 0, stream>>>(Wv, buf_ln, nullptr, buf_v, nullptr);

    // heads (concat layout [B,128,L]) into buf_dw
    k_attn<<<dim3(4, NH_, B_), 256, 0, stream>>>(buf_q, buf_k, buf_v, buf_dw);

    // d = Wo @ heads + res  (+stats of d)
    k_matmul<1, false, true, true><<<mb, 256, 0, stream>>>(Wo, buf_dw, buf_res, buf_res, P2);
    // e = LN(d)
    k_ln_apply<<<eg, 256, 0, stream>>>(buf_res, lnw, lnb, buf_ln, P2, 32, P1);
    // out = relu(W @ e) + d
    k_matmul<1, true, true, false><<<mb, 256, 0, stream>>>(Wf, buf_ln, buf_res, out, nullptr);
}

// Round 2
// 311.076 us; speedup vs baseline: 1.2486x; 1.2486x over previous
//
#include <hip/hip_runtime.h>
#include <hip/hip_bf16.h>

#define B_ 8
#define D_ 128
#define L_ 1024
#define KSZ 7
#define NH_ 8
#define DK_ 16

constexpr int BD = D_ * L_;                 // 131072 elements per batch
constexpr float LN_EPS = 1e-5f;
constexpr float INV_N = 1.0f / (float)BD;

// ---------- helpers ----------

__device__ __forceinline__ float2 ln_stats(const float2* __restrict__ part, int b, int npart) {
    float s = 0.f, q = 0.f;
    for (int i = 0; i < npart; ++i) { float2 p = part[b * 32 + i]; s += p.x; q += p.y; }
    float m = s * INV_N;
    float v = q * INV_N - m * m;
    return make_float2(m, rsqrtf(v + LN_EPS));
}

__device__ __forceinline__ void block_reduce_write(float s, float q, float2* slot, int tid) {
    __shared__ float reds[256];
    __shared__ float redq[256];
    reds[tid] = s; redq[tid] = q;
    __syncthreads();
    for (int off = 128; off > 0; off >>= 1) {
        if (tid < off) { reds[tid] += reds[tid + off]; redq[tid] += redq[tid + off]; }
        __syncthreads();
    }
    if (tid == 0) *slot = make_float2(reds[0], redq[0]);
}

// ---------- pos-enc add + stats ----------
__global__ __launch_bounds__(256) void k_addpos(
    const float* __restrict__ x, const float* __restrict__ pos,
    float* __restrict__ out, float2* __restrict__ part)
{
    int b = blockIdx.y, blk = blockIdx.x, tid = threadIdx.x;
    int base = b * BD + blk * 8192;
    int pbase = blk * 8192;
    const float4* x4 = (const float4*)(x + base);
    const float4* p4 = (const float4*)(pos + pbase);
    float4* o4 = (float4*)(out + base);
    float s = 0.f, q = 0.f;
    #pragma unroll
    for (int j = 0; j < 8; ++j) {
        int idx = j * 256 + tid;
        float4 xv = x4[idx], pv = p4[idx];
        float4 r = {xv.x + pv.x, xv.y + pv.y, xv.z + pv.z, xv.w + pv.w};
        o4[idx] = r;
        s += r.x + r.y + r.z + r.w;
        q += r.x * r.x + r.y * r.y + r.z * r.z + r.w * r.w;
    }
    block_reduce_write(s, q, part + b * 32 + blk, tid);
}

// ---------- LayerNorm apply (+ stats of output) ----------
__global__ __launch_bounds__(256) void k_ln_apply(
    const float* __restrict__ in, const float* __restrict__ lnw, const float* __restrict__ lnb,
    float* __restrict__ out, const float2* __restrict__ part_in, int npart,
    float2* __restrict__ part_out)
{
    int b = blockIdx.y, blk = blockIdx.x, tid = threadIdx.x;
    float2 st = ln_stats(part_in, b, npart);
    float mean = st.x, rstd = st.y;
    int base = b * BD + blk * 8192;
    int pbase = blk * 8192;
    const float4* i4  = (const float4*)(in + base);
    const float4* w4  = (const float4*)(lnw + pbase);
    const float4* bb4 = (const float4*)(lnb + pbase);
    float4* o4 = (float4*)(out + base);
    float s = 0.f, q = 0.f;
    #pragma unroll
    for (int j = 0; j < 8; ++j) {
        int idx = j * 256 + tid;
        float4 xv = i4[idx], w = w4[idx], bb = bb4[idx];
        float4 r;
        r.x = (xv.x - mean) * rstd * w.x + bb.x;
        r.y = (xv.y - mean) * rstd * w.y + bb.y;
        r.z = (xv.z - mean) * rstd * w.z + bb.z;
        r.w = (xv.w - mean) * rstd * w.w + bb.w;
        o4[idx] = r;
        s += r.x + r.y + r.z + r.w;
        q += r.x * r.x + r.y * r.y + r.z * r.z + r.w * r.w;
    }
    block_reduce_write(s, q, part_out + b * 32 + blk, tid);
}

// ---------- fused LayerNorm + depthwise conv (K=7, zero pad) ----------
__global__ __launch_bounds__(256) void k_ln_dw(
    const float* __restrict__ in, const float* __restrict__ lnw, const float* __restrict__ lnb,
    const float* __restrict__ dwk, float* __restrict__ out,
    const float2* __restrict__ part, int npart)
{
    int blk = blockIdx.x;
    int b = blk >> 7, d = blk & 127;
    int tid = threadIdx.x;
    float2 st = ln_stats(part, b, npart);
    float mean = st.x, rstd = st.y;
    __shared__ float row[L_ + 8];
    const float* inr = in + b * BD + d * L_;
    const float* wr  = lnw + d * L_;
    const float* br  = lnb + d * L_;
    #pragma unroll
    for (int j = 0; j < 4; ++j) {
        int l = j * 256 + tid;
        row[3 + l] = (inr[l] - mean) * rstd * wr[l] + br[l];
    }
    if (tid < 3) { row[tid] = 0.f; row[L_ + 3 + tid] = 0.f; }
    __syncthreads();
    float k0 = dwk[d*KSZ+0], k1 = dwk[d*KSZ+1], k2 = dwk[d*KSZ+2], k3 = dwk[d*KSZ+3],
          k4 = dwk[d*KSZ+4], k5 = dwk[d*KSZ+5], k6 = dwk[d*KSZ+6];
    float* outr = out + b * BD + d * L_;
    #pragma unroll
    for (int j = 0; j < 4; ++j) {
        int l = j * 256 + tid;
        outr[l] = k0*row[l]   + k1*row[l+1] + k2*row[l+2] + k3*row[l+3]
                + k4*row[l+4] + k5*row[l+5] + k6*row[l+6];
    }
}

// ---------- per-batch 128x128 @ 128x1024 matmul ----------
template<int WMODE, bool RELU, bool ADDRES, bool STATS>
__global__ __launch_bounds__(256) void k_matmul(
    const float* __restrict__ Wm, const float* __restrict__ X,
    const float* res, float* out, float2* part)
{
    int lt = blockIdx.x, rb = blockIdx.y, b = blockIdx.z;
    int tid = threadIdx.x;
    int l0 = lt * 64, r0 = rb * 64;
    __shared__ float Ws[D_][64];   // [c][o_local] (transposed)
    __shared__ float Xs[D_][64];   // [c][l_local]
    #pragma unroll
    for (int j = 0; j < 32; ++j) {
        int e = j * 256 + tid;
        int o = e & 63, c = e >> 6;
        int og = r0 + o;
        int woff;
        if constexpr (WMODE == 0)      woff = og * D_ + c;
        else if constexpr (WMODE == 1) woff = b * D_ * D_ + og * D_ + c;
        else                           woff = (og >> 4) * (B_ * DK_ * D_) + b * (DK_ * D_) + (og & 15) * D_ + c;
        Ws[c][o] = Wm[woff];
        Xs[c][o] = X[b * BD + c * L_ + l0 + o];
    }
    __syncthreads();
    int ty = tid >> 4, tx = tid & 15;
    float acc[4][4];
    #pragma unroll
    for (int r = 0; r < 4; ++r)
        #pragma unroll
        for (int j = 0; j < 4; ++j) acc[r][j] = 0.f;
    #pragma unroll 4
    for (int c = 0; c < D_; ++c) {
        float4 wv4 = *(const float4*)(&Ws[c][ty * 4]);
        float4 xv4 = *(const float4*)(&Xs[c][tx * 4]);
        float wv[4] = {wv4.x, wv4.y, wv4.z, wv4.w};
        float xv[4] = {xv4.x, xv4.y, xv4.z, xv4.w};
        #pragma unroll
        for (int r = 0; r < 4; ++r)
            #pragma unroll
            for (int j = 0; j < 4; ++j) acc[r][j] += wv[r] * xv[j];
    }
    float s = 0.f, q = 0.f;
    #pragma unroll
    for (int r = 0; r < 4; ++r) {
        int og = r0 + ty * 4 + r;
        float v[4];
        #pragma unroll
        for (int j = 0; j < 4; ++j) { v[j] = acc[r][j]; if constexpr (RELU) v[j] = fmaxf(v[j], 0.f); }
        if constexpr (ADDRES) {
            float4 rv = *(const float4*)(&res[b * BD + og * L_ + l0 + tx * 4]);
            v[0] += rv.x; v[1] += rv.y; v[2] += rv.z; v[3] += rv.w;
        }
        float4 ov = {v[0], v[1], v[2], v[3]};
        *(float4*)(&out[b * BD + og * L_ + l0 + tx * 4]) = ov;
        if constexpr (STATS) {
            s += v[0] + v[1] + v[2] + v[3];
            q += v[0]*v[0] + v[1]*v[1] + v[2]*v[2] + v[3]*v[3];
        }
    }
    if constexpr (STATS) block_reduce_write(s, q, part + b * 32 + rb * 16 + lt, tid);
}

// ---------- attention: softmax over l (query axis) per output column m ----------
// out[b, h*16+v, m] = sum_l V[v,l] * softmax_l(Q[:,l]·K[:,m] / 4)
// grid (16 mtiles, NH, B), block 256 = 4 l-slices x 64 m.
// Each thread: online softmax over l = s, s+4, s+8, ... (256 values), then
// 4-way merge per m via LDS. Wave == slice, so Q/V LDS reads are broadcast.
__global__ __launch_bounds__(256) void k_attn(
    const float* __restrict__ Qb, const float* __restrict__ Kb,
    const float* __restrict__ Vb, float* __restrict__ outb)
{
    int mt = blockIdx.x, h = blockIdx.y, b = blockIdx.z;
    int tid = threadIdx.x;
    int s = tid >> 6;        // l-slice 0..3 (== wave id)
    int ml = tid & 63;       // local m
    int m = mt * 64 + ml;
    const float* Qp = Qb + b * BD + (h * DK_) * L_;
    const float* Kp = Kb + b * BD + (h * DK_) * L_;
    const float* Vp = Vb + b * BD + (h * DK_) * L_;
    __shared__ float Qs[DK_][128];
    __shared__ float Vs[DK_][128];
    __shared__ float mrg[4 * 64 * (DK_ + 2)];
    float kreg[DK_];
    #pragma unroll
    for (int d = 0; d < DK_; ++d) kreg[d] = Kp[d * L_ + m] * 0.25f;  // fold 1/sqrt(DK)
    float mx = -1e30f, sm = 0.f;
    float acc[DK_];
    #pragma unroll
    for (int v = 0; v < DK_; ++v) acc[v] = 0.f;
    for (int lt = 0; lt < 8; ++lt) {
        __syncthreads();
        #pragma unroll
        for (int j = 0; j < 8; ++j) {
            int e = j * 256 + tid;
            int d = e >> 7, l = e & 127;
            Qs[d][l] = Qp[d * L_ + lt * 128 + l];
            Vs[d][l] = Vp[d * L_ + lt * 128 + l];
        }
        __syncthreads();
        // this thread handles l = s + 4*j within the tile, j = 0..31, in 2 chunks of 16
        #pragma unroll
        for (int lc = 0; lc < 2; ++lc) {
            float sv[16];
            #pragma unroll
            for (int j = 0; j < 16; ++j) sv[j] = 0.f;
            #pragma unroll
            for (int d = 0; d < DK_; ++d) {
                float kd = kreg[d];
                #pragma unroll
                for (int j = 0; j < 16; ++j) sv[j] += kd * Qs[d][s + 4 * (lc * 16 + j)];
            }
            float cm = mx;
            #pragma unroll
            for (int j = 0; j < 16; ++j) cm = fmaxf(cm, sv[j]);
            float fac = __expf(mx - cm);
            float wsum = 0.f;
            #pragma unroll
            for (int j = 0; j < 16; ++j) { sv[j] = __expf(sv[j] - cm); wsum += sv[j]; }
            sm = sm * fac + wsum;
            mx = cm;
            #pragma unroll
            for (int v = 0; v < DK_; ++v) {
                float a = acc[v] * fac;
                #pragma unroll
                for (int j = 0; j < 16; ++j) a += sv[j] * Vs[v][s + 4 * (lc * 16 + j)];
                acc[v] = a;
            }
        }
    }
    // merge the 4 slices per m
    __syncthreads();
    float* rec = &mrg[(s * 64 + ml) * (DK_ + 2)];
    rec[0] = mx; rec[1] = sm;
    #pragma unroll
    for (int v = 0; v < DK_; ++v) rec[2 + v] = acc[v];
    __syncthreads();
    if (s == 0) {
        float gm = -1e30f;
        #pragma unroll
        for (int s2 = 0; s2 < 4; ++s2) gm = fmaxf(gm, mrg[(s2 * 64 + ml) * (DK_ + 2)]);
        float gs = 0.f;
        float oacc[DK_];
        #pragma unroll
        for (int v = 0; v < DK_; ++v) oacc[v] = 0.f;
        #pragma unroll
        for (int s2 = 0; s2 < 4; ++s2) {
            const float* r2 = &mrg[(s2 * 64 + ml) * (DK_ + 2)];
            float f = __expf(r2[0] - gm);
            gs += r2[1] * f;
            #pragma unroll
            for (int v = 0; v < DK_; ++v) oacc[v] += r2[2 + v] * f;
        }
        float inv = 1.f / gs;
        #pragma unroll
        for (int v = 0; v < DK_; ++v)
            outb[b * BD + (h * DK_ + v) * L_ + m] = oacc[v] * inv;
    }
}

// ---------- launch ----------

extern "C" void kernel_launch(void* const* d_in, const int* in_sizes, int n_in,
                              void* d_out, int out_size, void* d_ws, size_t ws_size,
                              hipStream_t stream)
{
    const float* x   = (const float*)d_in[0];
    const float* pos = (const float*)d_in[1];
    const float* lnw = (const float*)d_in[2];
    const float* lnb = (const float*)d_in[3];
    const float* dw  = (const float*)d_in[4];
    const float* pw  = (const float*)d_in[5];
    const float* Wq  = (const float*)d_in[6];
    const float* Wk  = (const float*)d_in[7];
    const float* Wv  = (const float*)d_in[8];
    const float* Wo  = (const float*)d_in[9];
    const float* Wf  = (const float*)d_in[10];
    float* out = (float*)d_out;

    float* ws = (float*)d_ws;
    float2* P1 = (float2*)ws;               // 256 float2
    float2* P2 = (float2*)(ws + 512);       // 256 float2
    float* buf_res = ws + 1024;             // residual stream c_i
    float* buf_ln  = buf_res + (size_t)B_ * BD;
    float* buf_dw  = buf_ln  + (size_t)B_ * BD;  // depthwise out; later attn heads
    float* buf_q   = buf_dw  + (size_t)B_ * BD;
    float* buf_k   = buf_q   + (size_t)B_ * BD;
    float* buf_v   = buf_k   + (size_t)B_ * BD;

    dim3 eg(16, 8);        // elementwise grids
    dim3 mb(16, 2, 8);     // matmul grid

    // out = x + pos; res = out  (+stats for first LN)
    k_addpos<<<eg, 256, 0, stream>>>(x, pos, buf_res, P1);

    for (int i = 0; i < 4; ++i) {
        const float* src = (i == 0) ? buf_res : buf_ln;
        // dwout = depthwise(LN(src))
        k_ln_dw<<<1024, 256, 0, stream>>>(src, lnw, lnb, dw + i * D_ * KSZ, buf_dw, P1, 16);
        // c_i = relu(pw_i @ dwout) + res  (+stats of c_i)
        k_matmul<0, true, true, true><<<mb, 256, 0, stream>>>(pw + i * D_ * D_, buf_dw, buf_res, buf_res, P2);
        // b_i = LN(c_i)  (+stats of b_i for next iteration's LN)
        k_ln_apply<<<eg, 256, 0, stream>>>(buf_res, lnw, lnb, buf_ln, P2, 32, P1);
    }

    // Q/K/V = Wq/Wk/Wv (gathered per b) @ b_3
    k_matmul<2, false, false, false><<<mb, 256, 0, stream>>>(Wq, buf_ln, nullptr, buf_q, nullptr);
    k_matmul<2, false, false, false><<<mb, 256, 0, stream>>>(Wk, buf_ln, nullptr, buf_k, nullptr);
    k_matmul<2, false, false, false><<<mb, 256, 0, stream>>>(Wv, buf_ln, nullptr, buf_v, nullptr);

    // heads (concat layout [B,128,L]) into buf_dw
    k_attn<<<dim3(16, NH_, B_), 256, 0, stream>>>(buf_q, buf_k, buf_v, buf_dw);

    // d = Wo @ heads + res  (+stats of d)
    k_matmul<1, false, true, true><<<mb, 256, 0, stream>>>(Wo, buf_dw, buf_res, buf_res, P2);
    // e = LN(d)
    k_ln_apply<<<eg, 256, 0, stream>>>(buf_res, lnw, lnb, buf_ln, P2, 32, P1);
    // out = relu(W @ e) + d
    k_matmul<1, true, true, false><<<mb, 256, 0, stream>>>(Wf, buf_ln, buf_res, out, nullptr);
}

// Round 3
// 191.563 us; speedup vs baseline: 2.0276x; 1.6239x over previous
//
#include <hip/hip_runtime.h>
#include <hip/hip_bf16.h>

#define B_ 8
#define D_ 128
#define L_ 1024
#define KSZ 7
#define NH_ 8
#define DK_ 16

constexpr int BD = D_ * L_;                 // 131072 elements per batch
constexpr float LN_EPS = 1e-5f;
constexpr float INV_N = 1.0f / (float)BD;

typedef _Float16 half4 __attribute__((ext_vector_type(4)));
typedef float f32x4 __attribute__((ext_vector_type(4)));

// ---------- helpers ----------

__device__ __forceinline__ float2 ln_stats(const float2* __restrict__ part, int b, int npart) {
    float s = 0.f, q = 0.f;
    for (int i = 0; i < npart; ++i) { float2 p = part[b * 32 + i]; s += p.x; q += p.y; }
    float m = s * INV_N;
    float v = q * INV_N - m * m;
    return make_float2(m, rsqrtf(v + LN_EPS));
}

__device__ __forceinline__ void block_reduce_write(float s, float q, float2* slot, int tid) {
    __shared__ float reds[256];
    __shared__ float redq[256];
    reds[tid] = s; redq[tid] = q;
    __syncthreads();
    for (int off = 128; off > 0; off >>= 1) {
        if (tid < off) { reds[tid] += reds[tid + off]; redq[tid] += redq[tid + off]; }
        __syncthreads();
    }
    if (tid == 0) *slot = make_float2(reds[0], redq[0]);
}

// ---------- pos-enc add + stats ----------
__global__ __launch_bounds__(256) void k_addpos(
    const float* __restrict__ x, const float* __restrict__ pos,
    float* __restrict__ out, float2* __restrict__ part)
{
    int b = blockIdx.y, blk = blockIdx.x, tid = threadIdx.x;
    int base = b * BD + blk * 8192;
    int pbase = blk * 8192;
    const float4* x4 = (const float4*)(x + base);
    const float4* p4 = (const float4*)(pos + pbase);
    float4* o4 = (float4*)(out + base);
    float s = 0.f, q = 0.f;
    #pragma unroll
    for (int j = 0; j < 8; ++j) {
        int idx = j * 256 + tid;
        float4 xv = x4[idx], pv = p4[idx];
        float4 r = {xv.x + pv.x, xv.y + pv.y, xv.z + pv.z, xv.w + pv.w};
        o4[idx] = r;
        s += r.x + r.y + r.z + r.w;
        q += r.x * r.x + r.y * r.y + r.z * r.z + r.w * r.w;
    }
    block_reduce_write(s, q, part + b * 32 + blk, tid);
}

// ---------- LayerNorm apply (+ stats of output) ----------
__global__ __launch_bounds__(256) void k_ln_apply(
    const float* __restrict__ in, const float* __restrict__ lnw, const float* __restrict__ lnb,
    float* __restrict__ out, const float2* __restrict__ part_in, int npart,
    float2* __restrict__ part_out)
{
    int b = blockIdx.y, blk = blockIdx.x, tid = threadIdx.x;
    float2 st = ln_stats(part_in, b, npart);
    float mean = st.x, rstd = st.y;
    int base = b * BD + blk * 8192;
    int pbase = blk * 8192;
    const float4* i4  = (const float4*)(in + base);
    const float4* w4  = (const float4*)(lnw + pbase);
    const float4* bb4 = (const float4*)(lnb + pbase);
    float4* o4 = (float4*)(out + base);
    float s = 0.f, q = 0.f;
    #pragma unroll
    for (int j = 0; j < 8; ++j) {
        int idx = j * 256 + tid;
        float4 xv = i4[idx], w = w4[idx], bb = bb4[idx];
        float4 r;
        r.x = (xv.x - mean) * rstd * w.x + bb.x;
        r.y = (xv.y - mean) * rstd * w.y + bb.y;
        r.z = (xv.z - mean) * rstd * w.z + bb.z;
        r.w = (xv.w - mean) * rstd * w.w + bb.w;
        o4[idx] = r;
        s += r.x + r.y + r.z + r.w;
        q += r.x * r.x + r.y * r.y + r.z * r.z + r.w * r.w;
    }
    block_reduce_write(s, q, part_out + b * 32 + blk, tid);
}

// ---------- fused LayerNorm + depthwise conv (K=7, zero pad) ----------
__global__ __launch_bounds__(256) void k_ln_dw(
    const float* __restrict__ in, const float* __restrict__ lnw, const float* __restrict__ lnb,
    const float* __restrict__ dwk, float* __restrict__ out,
    const float2* __restrict__ part, int npart)
{
    int blk = blockIdx.x;
    int b = blk >> 7, d = blk & 127;
    int tid = threadIdx.x;
    float2 st = ln_stats(part, b, npart);
    float mean = st.x, rstd = st.y;
    __shared__ float row[L_ + 8];
    const float* inr = in + b * BD + d * L_;
    const float* wr  = lnw + d * L_;
    const float* br  = lnb + d * L_;
    #pragma unroll
    for (int j = 0; j < 4; ++j) {
        int l = j * 256 + tid;
        row[3 + l] = (inr[l] - mean) * rstd * wr[l] + br[l];
    }
    if (tid < 3) { row[tid] = 0.f; row[L_ + 3 + tid] = 0.f; }
    __syncthreads();
    float k0 = dwk[d*KSZ+0], k1 = dwk[d*KSZ+1], k2 = dwk[d*KSZ+2], k3 = dwk[d*KSZ+3],
          k4 = dwk[d*KSZ+4], k5 = dwk[d*KSZ+5], k6 = dwk[d*KSZ+6];
    float* outr = out + b * BD + d * L_;
    #pragma unroll
    for (int j = 0; j < 4; ++j) {
        int l = j * 256 + tid;
        outr[l] = k0*row[l]   + k1*row[l+1] + k2*row[l+2] + k3*row[l+3]
                + k4*row[l+4] + k5*row[l+5] + k6*row[l+6];
    }
}

// ---------- per-batch 128x128 @ 128x1024 matmul ----------
template<int WMODE, bool RELU, bool ADDRES, bool STATS>
__global__ __launch_bounds__(256) void k_matmul(
    const float* __restrict__ Wm, const float* __restrict__ X,
    const float* res, float* out, float2* part)
{
    int lt = blockIdx.x, rb = blockIdx.y, b = blockIdx.z;
    int tid = threadIdx.x;
    int l0 = lt * 64, r0 = rb * 64;
    __shared__ float Ws[D_][64];   // [c][o_local] (transposed)
    __shared__ float Xs[D_][64];   // [c][l_local]
    #pragma unroll
    for (int j = 0; j < 32; ++j) {
        int e = j * 256 + tid;
        int o = e & 63, c = e >> 6;
        int og = r0 + o;
        int woff;
        if constexpr (WMODE == 0)      woff = og * D_ + c;
        else if constexpr (WMODE == 1) woff = b * D_ * D_ + og * D_ + c;
        else                           woff = (og >> 4) * (B_ * DK_ * D_) + b * (DK_ * D_) + (og & 15) * D_ + c;
        Ws[c][o] = Wm[woff];
        Xs[c][o] = X[b * BD + c * L_ + l0 + o];
    }
    __syncthreads();
    int ty = tid >> 4, tx = tid & 15;
    float acc[4][4];
    #pragma unroll
    for (int r = 0; r < 4; ++r)
        #pragma unroll
        for (int j = 0; j < 4; ++j) acc[r][j] = 0.f;
    #pragma unroll 4
    for (int c = 0; c < D_; ++c) {
        float4 wv4 = *(const float4*)(&Ws[c][ty * 4]);
        float4 xv4 = *(const float4*)(&Xs[c][tx * 4]);
        float wv[4] = {wv4.x, wv4.y, wv4.z, wv4.w};
        float xv[4] = {xv4.x, xv4.y, xv4.z, xv4.w};
        #pragma unroll
        for (int r = 0; r < 4; ++r)
            #pragma unroll
            for (int j = 0; j < 4; ++j) acc[r][j] += wv[r] * xv[j];
    }
    float s = 0.f, q = 0.f;
    #pragma unroll
    for (int r = 0; r < 4; ++r) {
        int og = r0 + ty * 4 + r;
        float v[4];
        #pragma unroll
        for (int j = 0; j < 4; ++j) { v[j] = acc[r][j]; if constexpr (RELU) v[j] = fmaxf(v[j], 0.f); }
        if constexpr (ADDRES) {
            float4 rv = *(const float4*)(&res[b * BD + og * L_ + l0 + tx * 4]);
            v[0] += rv.x; v[1] += rv.y; v[2] += rv.z; v[3] += rv.w;
        }
        float4 ov = {v[0], v[1], v[2], v[3]};
        *(float4*)(&out[b * BD + og * L_ + l0 + tx * 4]) = ov;
        if constexpr (STATS) {
            s += v[0] + v[1] + v[2] + v[3];
            q += v[0]*v[0] + v[1]*v[1] + v[2]*v[2] + v[3]*v[3];
        }
    }
    if constexpr (STATS) block_reduce_write(s, q, part + b * 32 + rb * 16 + lt, tid);
}

// ---------- MFMA flash attention (softmax over l, the "key" axis here) ----------
// out[b, h*16+v, m] = sum_l V[v,l] * softmax_l(Q[:,l]·K[:,m] / 4)
// Swapped-operand scheme with v_mfma_f32_16x16x16_f16:
//   S^T[l,m] tile = mfma(A=Q^T[l x d], B=K[d x m])  -> C: col m = lane&15, row l = (lane>>4)*4+reg
//   softmax over l: 15 in-lane ops + shfl_xor(16) + shfl_xor(32)
//   P stays in-register: B-frag for PV needs k(l) = (lane>>4)*4+j  == the C regs exactly
//   out^T[v,m] = mfma(A=V[v x l], B=P[l x m]) accumulated over all l-tiles
// Block = 256 threads = 4 waves; each wave owns 16 m; block covers 64 m of one (b,h).
__global__ __launch_bounds__(256) void k_attn_mfma(
    const float* __restrict__ Qb, const float* __restrict__ Kb,
    const float* __restrict__ Vb, float* __restrict__ outb)
{
    constexpr int QSTR = 20;   // f16 elems per Q_ldsT row (16 + 4 pad) -> 40B stride, conflict-free b64 reads
    constexpr int VSTR = 72;   // f16 elems per V_lds row (64 + 8 pad) -> 144B stride, 2-way (free) b64 reads
    __shared__ _Float16 Qs[64 * QSTR];   // [l_local][d]
    __shared__ _Float16 Vs[16 * VSTR];   // [v][l_local]
    int mt = blockIdx.x, h = blockIdx.y, b = blockIdx.z;
    int tid = threadIdx.x;
    int w    = tid >> 6;
    int lane = tid & 63;
    int lg   = lane >> 4;      // lane group 0..3
    int ln   = lane & 15;
    int m = mt * 64 + w * 16 + ln;
    const float* Qp = Qb + b * BD + (h * DK_) * L_;
    const float* Kp = Kb + b * BD + (h * DK_) * L_;
    const float* Vp = Vb + b * BD + (h * DK_) * L_;

    // K B-fragment (fixed per wave): element (k=d=lg*4+j, col=m); fold 1/sqrt(DK)=0.25
    half4 kfrag;
    #pragma unroll
    for (int j = 0; j < 4; ++j)
        kfrag[j] = (_Float16)(Kp[(lg * 4 + j) * L_ + m] * 0.25f);

    f32x4 acc = {0.f, 0.f, 0.f, 0.f};   // out^T frag: row v = lg*4+r, col m
    float run_mx = -1e30f, run_sm = 0.f;

    int sd  = tid >> 4;        // 0..15: d-row for Q staging, v-row for V staging
    int slq = tid & 15;        // quad index along l

    for (int lt = 0; lt < 16; ++lt) {
        int l0 = lt * 64;
        __syncthreads();
        {   // stage Q (transposed) and V for this 64-l tile, fp32 -> f16
            float4 qv = *(const float4*)(&Qp[sd * L_ + l0 + slq * 4]);
            Qs[(slq*4+0)*QSTR + sd] = (_Float16)qv.x;
            Qs[(slq*4+1)*QSTR + sd] = (_Float16)qv.y;
            Qs[(slq*4+2)*QSTR + sd] = (_Float16)qv.z;
            Qs[(slq*4+3)*QSTR + sd] = (_Float16)qv.w;
            float4 vv = *(const float4*)(&Vp[sd * L_ + l0 + slq * 4]);
            half4 vh = {(_Float16)vv.x, (_Float16)vv.y, (_Float16)vv.z, (_Float16)vv.w};
            *(half4*)(&Vs[sd * VSTR + slq * 4]) = vh;
        }
        __syncthreads();

        // S^T subtiles f = 0..3 (16 l each)
        f32x4 s[4];
        #pragma unroll
        for (int f = 0; f < 4; ++f) {
            half4 qfrag = *(const half4*)(&Qs[(f * 16 + ln) * QSTR + lg * 4]);
            f32x4 z = {0.f, 0.f, 0.f, 0.f};
            s[f] = __builtin_amdgcn_mfma_f32_16x16x16f16(qfrag, kfrag, z, 0, 0, 0);
        }

        // online softmax over the tile's 64 l values (per column m)
        float tm = -1e30f;
        #pragma unroll
        for (int f = 0; f < 4; ++f)
            #pragma unroll
            for (int r = 0; r < 4; ++r) tm = fmaxf(tm, s[f][r]);
        tm = fmaxf(tm, __shfl_xor(tm, 16, 64));
        tm = fmaxf(tm, __shfl_xor(tm, 32, 64));
        float nm = fmaxf(run_mx, tm);
        float fac = __expf(run_mx - nm);
        run_mx = nm;

        float ts = 0.f;
        half4 pf[4];
        #pragma unroll
        for (int f = 0; f < 4; ++f) {
            float p0 = __expf(s[f][0] - nm);
            float p1 = __expf(s[f][1] - nm);
            float p2 = __expf(s[f][2] - nm);
            float p3 = __expf(s[f][3] - nm);
            ts += (p0 + p1) + (p2 + p3);
            pf[f][0] = (_Float16)p0; pf[f][1] = (_Float16)p1;
            pf[f][2] = (_Float16)p2; pf[f][3] = (_Float16)p3;
        }
        ts += __shfl_xor(ts, 16, 64);
        ts += __shfl_xor(ts, 32, 64);
        run_sm = run_sm * fac + ts;

        acc[0] *= fac; acc[1] *= fac; acc[2] *= fac; acc[3] *= fac;

        // PV: out^T += V * P, per 16-l subtile
        #pragma unroll
        for (int f = 0; f < 4; ++f) {
            half4 vfrag = *(const half4*)(&Vs[ln * VSTR + f * 16 + lg * 4]);
            acc = __builtin_amdgcn_mfma_f32_16x16x16f16(vfrag, pf[f], acc, 0, 0, 0);
        }
    }

    float inv = 1.f / run_sm;
    #pragma unroll
    for (int r = 0; r < 4; ++r)
        outb[b * BD + (h * DK_ + lg * 4 + r) * L_ + m] = acc[r] * inv;
}

// ---------- launch ----------

extern "C" void kernel_launch(void* const* d_in, const int* in_sizes, int n_in,
                              void* d_out, int out_size, void* d_ws, size_t ws_size,
                              hipStream_t stream)
{
    const float* x   = (const float*)d_in[0];
    const float* pos = (const float*)d_in[1];
    const float* lnw = (const float*)d_in[2];
    const float* lnb = (const float*)d_in[3];
    const float* dw  = (const float*)d_in[4];
    const float* pw  = (const float*)d_in[5];
    const float* Wq  = (const float*)d_in[6];
    const float* Wk  = (const float*)d_in[7];
    const float* Wv  = (const float*)d_in[8];
    const float* Wo  = (const float*)d_in[9];
    const float* Wf  = (const float*)d_in[10];
    float* out = (float*)d_out;

    float* ws = (float*)d_ws;
    float2* P1 = (float2*)ws;               // 256 float2
    float2* P2 = (float2*)(ws + 512);       // 256 float2
    float* buf_res = ws + 1024;             // residual stream c_i
    float* buf_ln  = buf_res + (size_t)B_ * BD;
    float* buf_dw  = buf_ln  + (size_t)B_ * BD;  // depthwise out; later attn heads
    float* buf_q   = buf_dw  + (size_t)B_ * BD;
    float* buf_k   = buf_q   + (size_t)B_ * BD;
    float* buf_v   = buf_k   + (size_t)B_ * BD;

    dim3 eg(16, 8);        // elementwise grids
    dim3 mb(16, 2, 8);     // matmul grid

    // out = x + pos; res = out  (+stats for first LN)
    k_addpos<<<eg, 256, 0, stream>>>(x, pos, buf_res, P1);

    for (int i = 0; i < 4; ++i) {
        const float* src = (i == 0) ? buf_res : buf_ln;
        // dwout = depthwise(LN(src))
        k_ln_dw<<<1024, 256, 0, stream>>>(src, lnw, lnb, dw + i * D_ * KSZ, buf_dw, P1, 16);
        // c_i = relu(pw_i @ dwout) + res  (+stats of c_i)
        k_matmul<0, true, true, true><<<mb, 256, 0, stream>>>(pw + i * D_ * D_, buf_dw, buf_res, buf_res, P2);
        // b_i = LN(c_i)  (+stats of b_i for next iteration's LN)
        k_ln_apply<<<eg, 256, 0, stream>>>(buf_res, lnw, lnb, buf_ln, P2, 32, P1);
    }

    // Q/K/V = Wq/Wk/Wv (gathered per b) @ b_3
    k_matmul<2, false, false, false><<<mb, 256, 0, stream>>>(Wq, buf_ln, nullptr, buf_q, nullptr);
    k_matmul<2, false, false, false><<<mb, 256, 0, stream>>>(Wk, buf_ln, nullptr, buf_k, nullptr);
    k_matmul<2, false, false, false><<<mb, 256, 0, stream>>>(Wv, buf_ln, nullptr, buf_v, nullptr);

    // heads (concat layout [B,128,L]) into buf_dw
    k_attn_mfma<<<dim3(16, NH_, B_), 256, 0, stream>>>(buf_q, buf_k, buf_v, buf_dw);

    // d = Wo @ heads + res  (+stats of d)
    k_matmul<1, false, true, true><<<mb, 256, 0, stream>>>(Wo, buf_dw, buf_res, buf_res, P2);
    // e = LN(d)
    k_ln_apply<<<eg, 256, 0, stream>>>(buf_res, lnw, lnb, buf_ln, P2, 32, P1);
    // out = relu(W @ e) + d
    k_matmul<1, true, true, false><<<mb, 256, 0, stream>>>(Wf, buf_ln, buf_res, out, nullptr);
}

// Round 4
// 158.058 us; speedup vs baseline: 2.4574x; 1.2120x over previous
//
#include <hip/hip_runtime.h>
#include <hip/hip_bf16.h>

#define B_ 8
#define D_ 128
#define L_ 1024
#define KSZ 7
#define NH_ 8
#define DK_ 16

constexpr int BD = D_ * L_;                 // 131072 elements per batch
constexpr float LN_EPS = 1e-5f;
constexpr float INV_N = 1.0f / (float)BD;

typedef _Float16 half4 __attribute__((ext_vector_type(4)));
typedef float f32x4 __attribute__((ext_vector_type(4)));

// ---------- helpers ----------

__device__ __forceinline__ float2 ln_stats(const float2* __restrict__ part, int b, int npart) {
    float s = 0.f, q = 0.f;
    for (int i = 0; i < npart; ++i) { float2 p = part[b * 32 + i]; s += p.x; q += p.y; }
    float m = s * INV_N;
    float v = q * INV_N - m * m;
    return make_float2(m, rsqrtf(v + LN_EPS));
}

__device__ __forceinline__ void block_reduce_write(float s, float q, float2* slot, int tid) {
    __shared__ float reds[256];
    __shared__ float redq[256];
    reds[tid] = s; redq[tid] = q;
    __syncthreads();
    for (int off = 128; off > 0; off >>= 1) {
        if (tid < off) { reds[tid] += reds[tid + off]; redq[tid] += redq[tid + off]; }
        __syncthreads();
    }
    if (tid == 0) *slot = make_float2(reds[0], redq[0]);
}

// ---------- pos-enc add + stats ----------
// grid (32, 8), block 256; each block covers 4096 contiguous elements of one batch
__global__ __launch_bounds__(256) void k_addpos(
    const float* __restrict__ x, const float* __restrict__ pos,
    float* __restrict__ out, float2* __restrict__ part)
{
    int b = blockIdx.y, blk = blockIdx.x, tid = threadIdx.x;
    int base = b * BD + blk * 4096;
    int pbase = blk * 4096;
    const float4* x4 = (const float4*)(x + base);
    const float4* p4 = (const float4*)(pos + pbase);
    float4* o4 = (float4*)(out + base);
    float s = 0.f, q = 0.f;
    #pragma unroll
    for (int j = 0; j < 4; ++j) {
        int idx = j * 256 + tid;
        float4 xv = x4[idx], pv = p4[idx];
        float4 r = {xv.x + pv.x, xv.y + pv.y, xv.z + pv.z, xv.w + pv.w};
        o4[idx] = r;
        s += r.x + r.y + r.z + r.w;
        q += r.x * r.x + r.y * r.y + r.z * r.z + r.w * r.w;
    }
    block_reduce_write(s, q, part + b * 32 + blk, tid);
}

// ---------- LayerNorm apply (+ stats of output) ----------
__global__ __launch_bounds__(256) void k_ln_apply(
    const float* __restrict__ in, const float* __restrict__ lnw, const float* __restrict__ lnb,
    float* __restrict__ out, const float2* __restrict__ part_in, int npart,
    float2* __restrict__ part_out)
{
    int b = blockIdx.y, blk = blockIdx.x, tid = threadIdx.x;
    float2 st = ln_stats(part_in, b, npart);
    float mean = st.x, rstd = st.y;
    int base = b * BD + blk * 4096;
    int pbase = blk * 4096;
    const float4* i4  = (const float4*)(in + base);
    const float4* w4  = (const float4*)(lnw + pbase);
    const float4* bb4 = (const float4*)(lnb + pbase);
    float4* o4 = (float4*)(out + base);
    float s = 0.f, q = 0.f;
    #pragma unroll
    for (int j = 0; j < 4; ++j) {
        int idx = j * 256 + tid;
        float4 xv = i4[idx], w = w4[idx], bb = bb4[idx];
        float4 r;
        r.x = (xv.x - mean) * rstd * w.x + bb.x;
        r.y = (xv.y - mean) * rstd * w.y + bb.y;
        r.z = (xv.z - mean) * rstd * w.z + bb.z;
        r.w = (xv.w - mean) * rstd * w.w + bb.w;
        o4[idx] = r;
        s += r.x + r.y + r.z + r.w;
        q += r.x * r.x + r.y * r.y + r.z * r.z + r.w * r.w;
    }
    block_reduce_write(s, q, part_out + b * 32 + blk, tid);
}

// ---------- fused LayerNorm + depthwise conv (K=7, zero pad) ----------
__global__ __launch_bounds__(256) void k_ln_dw(
    const float* __restrict__ in, const float* __restrict__ lnw, const float* __restrict__ lnb,
    const float* __restrict__ dwk, float* __restrict__ out,
    const float2* __restrict__ part, int npart)
{
    int blk = blockIdx.x;
    int b = blk >> 7, d = blk & 127;
    int tid = threadIdx.x;
    float2 st = ln_stats(part, b, npart);
    float mean = st.x, rstd = st.y;
    __shared__ float row[L_ + 8];
    const float* inr = in + b * BD + d * L_;
    const float* wr  = lnw + d * L_;
    const float* br  = lnb + d * L_;
    #pragma unroll
    for (int j = 0; j < 4; ++j) {
        int l = j * 256 + tid;
        row[3 + l] = (inr[l] - mean) * rstd * wr[l] + br[l];
    }
    if (tid < 3) { row[tid] = 0.f; row[L_ + 3 + tid] = 0.f; }
    __syncthreads();
    float k0 = dwk[d*KSZ+0], k1 = dwk[d*KSZ+1], k2 = dwk[d*KSZ+2], k3 = dwk[d*KSZ+3],
          k4 = dwk[d*KSZ+4], k5 = dwk[d*KSZ+5], k6 = dwk[d*KSZ+6];
    float* outr = out + b * BD + d * L_;
    #pragma unroll
    for (int j = 0; j < 4; ++j) {
        int l = j * 256 + tid;
        outr[l] = k0*row[l]   + k1*row[l+1] + k2*row[l+2] + k3*row[l+3]
                + k4*row[l+4] + k5*row[l+5] + k6*row[l+6];
    }
}

// ---------- MFMA per-batch 128x128 @ 128x1024 matmul ----------
// C[o,l] = sum_c W[o,c] X[c,l].  Fragment mapping (verified by attn kernel):
//   A: lane(lg,ln) holds A[row=ln][k=lg*4+j]       (W rows read direct from global, L1/L2-hot)
//   B: lane(lg,ln) holds B[k=lg*4+j][col=ln]       (from LDS-staged X^T f16, 132-elem stride)
//   C: lane(lg,ln) holds C[row=lg*4+r][col=ln]
// Block 256 thr = 4 waves; tile 64o x 64l; wave w -> o rows r0+w*16..+15.
// WMODE 0: W[o,c]; 1: W[b,o,c]; 2: W[h,b,dk,c] with o=h*16+dk.
template<int WMODE, bool RELU, bool ADDRES, bool STATS>
__global__ __launch_bounds__(256) void k_matmul_mfma(
    const float* __restrict__ Wm, const float* __restrict__ X,
    const float* __restrict__ res, float* __restrict__ out, float2* __restrict__ part)
{
    constexpr int XSTR = 132;                 // f16 elems per X^T row (128 + 4 pad), 264B stride
    __shared__ _Float16 Xt[64 * XSTR];        // [l_local][c]
    int lt = blockIdx.x, rb = blockIdx.y, b = blockIdx.z;
    int tid = threadIdx.x;
    int l0 = lt * 64, r0 = rb * 64;

    // stage X^T tile (fp32 [c][l] -> f16 [l][c])
    {
        int c = tid >> 1, lh = tid & 1;
        const float* xp = X + b * BD + c * L_ + l0 + lh * 32;
        #pragma unroll
        for (int q = 0; q < 8; ++q) {
            float4 v = *(const float4*)(xp + q * 4);
            int lb = lh * 32 + q * 4;
            Xt[(lb + 0) * XSTR + c] = (_Float16)v.x;
            Xt[(lb + 1) * XSTR + c] = (_Float16)v.y;
            Xt[(lb + 2) * XSTR + c] = (_Float16)v.z;
            Xt[(lb + 3) * XSTR + c] = (_Float16)v.w;
        }
    }
    __syncthreads();

    int w = tid >> 6, lane = tid & 63, lg = lane >> 4, ln = lane & 15;
    int o = r0 + w * 16 + ln;                 // A-frag row owned by this lane
    const float* wrow;
    if constexpr (WMODE == 0)      wrow = Wm + o * D_;
    else if constexpr (WMODE == 1) wrow = Wm + b * D_ * D_ + o * D_;
    else                           wrow = Wm + (o >> 4) * (B_ * DK_ * D_) + b * (DK_ * D_) + (o & 15) * D_;

    f32x4 acc[4];
    #pragma unroll
    for (int n = 0; n < 4; ++n) acc[n] = (f32x4){0.f, 0.f, 0.f, 0.f};

    #pragma unroll
    for (int kk = 0; kk < 8; ++kk) {
        float4 wv = *(const float4*)(wrow + kk * 16 + lg * 4);
        half4 af = {(_Float16)wv.x, (_Float16)wv.y, (_Float16)wv.z, (_Float16)wv.w};
        #pragma unroll
        for (int n = 0; n < 4; ++n) {
            half4 bf = *(const half4*)(&Xt[(n * 16 + ln) * XSTR + kk * 16 + lg * 4]);
            acc[n] = __builtin_amdgcn_mfma_f32_16x16x16f16(af, bf, acc[n], 0, 0, 0);
        }
    }

    // epilogue: relu / +res / store / stats.  C row = lg*4+r, col = ln.
    float s = 0.f, q = 0.f;
    #pragma unroll
    for (int n = 0; n < 4; ++n) {
        #pragma unroll
        for (int r = 0; r < 4; ++r) {
            int og = r0 + w * 16 + lg * 4 + r;
            int idx = b * BD + og * L_ + l0 + n * 16 + ln;
            float v = acc[n][r];
            if constexpr (RELU) v = fmaxf(v, 0.f);
            if constexpr (ADDRES) v += res[idx];
            out[idx] = v;
            if constexpr (STATS) { s += v; q += v * v; }
        }
    }
    if constexpr (STATS) block_reduce_write(s, q, part + b * 32 + rb * 16 + lt, tid);
}

// ---------- MFMA flash attention (softmax over l, the "key" axis here) ----------
__global__ __launch_bounds__(256) void k_attn_mfma(
    const float* __restrict__ Qb, const float* __restrict__ Kb,
    const float* __restrict__ Vb, float* __restrict__ outb)
{
    constexpr int QSTR = 20;   // f16 elems per Q_ldsT row (16 + 4 pad)
    constexpr int VSTR = 72;   // f16 elems per V_lds row (64 + 8 pad)
    __shared__ _Float16 Qs[64 * QSTR];   // [l_local][d]
    __shared__ _Float16 Vs[16 * VSTR];   // [v][l_local]
    int mt = blockIdx.x, h = blockIdx.y, b = blockIdx.z;
    int tid = threadIdx.x;
    int w    = tid >> 6;
    int lane = tid & 63;
    int lg   = lane >> 4;
    int ln   = lane & 15;
    int m = mt * 64 + w * 16 + ln;
    const float* Qp = Qb + b * BD + (h * DK_) * L_;
    const float* Kp = Kb + b * BD + (h * DK_) * L_;
    const float* Vp = Vb + b * BD + (h * DK_) * L_;

    half4 kfrag;
    #pragma unroll
    for (int j = 0; j < 4; ++j)
        kfrag[j] = (_Float16)(Kp[(lg * 4 + j) * L_ + m] * 0.25f);

    f32x4 acc = {0.f, 0.f, 0.f, 0.f};
    float run_mx = -1e30f, run_sm = 0.f;

    int sd  = tid >> 4;
    int slq = tid & 15;

    for (int lt = 0; lt < 16; ++lt) {
        int l0 = lt * 64;
        __syncthreads();
        {
            float4 qv = *(const float4*)(&Qp[sd * L_ + l0 + slq * 4]);
            Qs[(slq*4+0)*QSTR + sd] = (_Float16)qv.x;
            Qs[(slq*4+1)*QSTR + sd] = (_Float16)qv.y;
            Qs[(slq*4+2)*QSTR + sd] = (_Float16)qv.z;
            Qs[(slq*4+3)*QSTR + sd] = (_Float16)qv.w;
            float4 vv = *(const float4*)(&Vp[sd * L_ + l0 + slq * 4]);
            half4 vh = {(_Float16)vv.x, (_Float16)vv.y, (_Float16)vv.z, (_Float16)vv.w};
            *(half4*)(&Vs[sd * VSTR + slq * 4]) = vh;
        }
        __syncthreads();

        f32x4 s[4];
        #pragma unroll
        for (int f = 0; f < 4; ++f) {
            half4 qfrag = *(const half4*)(&Qs[(f * 16 + ln) * QSTR + lg * 4]);
            f32x4 z = {0.f, 0.f, 0.f, 0.f};
            s[f] = __builtin_amdgcn_mfma_f32_16x16x16f16(qfrag, kfrag, z, 0, 0, 0);
        }

        float tm = -1e30f;
        #pragma unroll
        for (int f = 0; f < 4; ++f)
            #pragma unroll
            for (int r = 0; r < 4; ++r) tm = fmaxf(tm, s[f][r]);
        tm = fmaxf(tm, __shfl_xor(tm, 16, 64));
        tm = fmaxf(tm, __shfl_xor(tm, 32, 64));
        float nm = fmaxf(run_mx, tm);
        float fac = __expf(run_mx - nm);
        run_mx = nm;

        float ts = 0.f;
        half4 pf[4];
        #pragma unroll
        for (int f = 0; f < 4; ++f) {
            float p0 = __expf(s[f][0] - nm);
            float p1 = __expf(s[f][1] - nm);
            float p2 = __expf(s[f][2] - nm);
            float p3 = __expf(s[f][3] - nm);
            ts += (p0 + p1) + (p2 + p3);
            pf[f][0] = (_Float16)p0; pf[f][1] = (_Float16)p1;
            pf[f][2] = (_Float16)p2; pf[f][3] = (_Float16)p3;
        }
        ts += __shfl_xor(ts, 16, 64);
        ts += __shfl_xor(ts, 32, 64);
        run_sm = run_sm * fac + ts;

        acc[0] *= fac; acc[1] *= fac; acc[2] *= fac; acc[3] *= fac;

        #pragma unroll
        for (int f = 0; f < 4; ++f) {
            half4 vfrag = *(const half4*)(&Vs[ln * VSTR + f * 16 + lg * 4]);
            acc = __builtin_amdgcn_mfma_f32_16x16x16f16(vfrag, pf[f], acc, 0, 0, 0);
        }
    }

    float inv = 1.f / run_sm;
    #pragma unroll
    for (int r = 0; r < 4; ++r)
        outb[b * BD + (h * DK_ + lg * 4 + r) * L_ + m] = acc[r] * inv;
}

// ---------- launch ----------

extern "C" void kernel_launch(void* const* d_in, const int* in_sizes, int n_in,
                              void* d_out, int out_size, void* d_ws, size_t ws_size,
                              hipStream_t stream)
{
    const float* x   = (const float*)d_in[0];
    const float* pos = (const float*)d_in[1];
    const float* lnw = (const float*)d_in[2];
    const float* lnb = (const float*)d_in[3];
    const float* dw  = (const float*)d_in[4];
    const float* pw  = (const float*)d_in[5];
    const float* Wq  = (const float*)d_in[6];
    const float* Wk  = (const float*)d_in[7];
    const float* Wv  = (const float*)d_in[8];
    const float* Wo  = (const float*)d_in[9];
    const float* Wf  = (const float*)d_in[10];
    float* out = (float*)d_out;

    float* ws = (float*)d_ws;
    float2* P1 = (float2*)ws;               // 256 float2
    float2* P2 = (float2*)(ws + 512);       // 256 float2
    float* buf_res = ws + 1024;             // residual stream c_i
    float* buf_ln  = buf_res + (size_t)B_ * BD;
    float* buf_dw  = buf_ln  + (size_t)B_ * BD;  // depthwise out; later attn heads
    float* buf_q   = buf_dw  + (size_t)B_ * BD;
    float* buf_k   = buf_q   + (size_t)B_ * BD;
    float* buf_v   = buf_k   + (size_t)B_ * BD;

    dim3 eg(32, 8);        // elementwise grids (256 blocks)
    dim3 mb(16, 2, 8);     // matmul grid

    // out = x + pos; res = out  (+stats for first LN)
    k_addpos<<<eg, 256, 0, stream>>>(x, pos, buf_res, P1);

    for (int i = 0; i < 4; ++i) {
        const float* src = (i == 0) ? buf_res : buf_ln;
        // dwout = depthwise(LN(src))
        k_ln_dw<<<1024, 256, 0, stream>>>(src, lnw, lnb, dw + i * D_ * KSZ, buf_dw, P1, 32);
        // c_i = relu(pw_i @ dwout) + res  (+stats of c_i)
        k_matmul_mfma<0, true, true, true><<<mb, 256, 0, stream>>>(pw + i * D_ * D_, buf_dw, buf_res, buf_res, P2);
        // b_i = LN(c_i)  (+stats of b_i for next iteration's LN)
        k_ln_apply<<<eg, 256, 0, stream>>>(buf_res, lnw, lnb, buf_ln, P2, 32, P1);
    }

    // Q/K/V = Wq/Wk/Wv (gathered per b) @ b_3
    k_matmul_mfma<2, false, false, false><<<mb, 256, 0, stream>>>(Wq, buf_ln, nullptr, buf_q, nullptr);
    k_matmul_mfma<2, false, false, false><<<mb, 256, 0, stream>>>(Wk, buf_ln, nullptr, buf_k, nullptr);
    k_matmul_mfma<2, false, false, false><<<mb, 256, 0, stream>>>(Wv, buf_ln, nullptr, buf_v, nullptr);

    // heads (concat layout [B,128,L]) into buf_dw
    k_attn_mfma<<<dim3(16, NH_, B_), 256, 0, stream>>>(buf_q, buf_k, buf_v, buf_dw);

    // d = Wo @ heads + res  (+stats of d)
    k_matmul_mfma<1, false, true, true><<<mb, 256, 0, stream>>>(Wo, buf_dw, buf_res, buf_res, P2);
    // e = LN(d)
    k_ln_apply<<<eg, 256, 0, stream>>>(buf_res, lnw, lnb, buf_ln, P2, 32, P1);
    // out = relu(W @ e) + d
    k_matmul_mfma<1, true, true, false><<<mb, 256, 0, stream>>>(Wf, buf_ln, buf_res, out, nullptr);
}